// Round 4
// baseline (25128.049 us; speedup 1.0000x reference)
//
#include <hip/hip_runtime.h>
#include <stdint.h>

#define SEQ 8192
#define EMB 1024
#define HID 2048
#define NCH 256

#define SCAN_B 64                   // persistent blocks (co-resident, proven R1-R6)
#define SCAN_T 512                  // 8 waves/block
#define ROWS_PB (HID / SCAN_B)      // 32 rows per block (4 per wave)
#define SENT 0xFFFFFFFFu            // poison: tanh never produces this pattern
#define NREP 4                      // ring replicas (spread L3 line ownership)
#define NSLOT 8                     // ring slots (skew<=1 proven; margin 4)

typedef unsigned uint4v __attribute__((ext_vector_type(4)));
typedef unsigned long long u64;

// ---------------------------------------------------------------------------
// Generic fp32 "TN" GEMM: C[m][n] = bias[n] + dot(X[m][:], W[n][:])
// ---------------------------------------------------------------------------
__global__ __launch_bounds__(256) void gemm_tn(const float* __restrict__ X,
                                               const float* __restrict__ W,
                                               const float* __restrict__ bias,
                                               float* __restrict__ C,
                                               int M, int N, int K)
{
    __shared__ float Xs[16][68];
    __shared__ float Ws[16][68];
    const int m0 = blockIdx.x * 64, n0 = blockIdx.y * 64;
    const int tid  = threadIdx.x;
    const int lrow = tid >> 2;
    const int kq   = (tid & 3) * 4;
    const int tx   = tid & 15, ty = tid >> 4;
    float acc[4][4] = {};
    const float* Xp = X + (size_t)(m0 + lrow) * K + kq;
    const float* Wp = W + (size_t)(n0 + lrow) * K + kq;

    for (int k0 = 0; k0 < K; k0 += 16) {
        float4 xv = *(const float4*)(Xp + k0);
        float4 wv = *(const float4*)(Wp + k0);
        __syncthreads();
        Xs[kq+0][lrow] = xv.x; Xs[kq+1][lrow] = xv.y;
        Xs[kq+2][lrow] = xv.z; Xs[kq+3][lrow] = xv.w;
        Ws[kq+0][lrow] = wv.x; Ws[kq+1][lrow] = wv.y;
        Ws[kq+2][lrow] = wv.z; Ws[kq+3][lrow] = wv.w;
        __syncthreads();
#pragma unroll
        for (int kk = 0; kk < 16; ++kk) {
            float4 av = *(const float4*)&Xs[kk][ty * 4];
            float4 bv = *(const float4*)&Ws[kk][tx * 4];
            float a[4] = {av.x, av.y, av.z, av.w};
            float b[4] = {bv.x, bv.y, bv.z, bv.w};
#pragma unroll
            for (int i = 0; i < 4; ++i)
#pragma unroll
                for (int j = 0; j < 4; ++j)
                    acc[i][j] += a[i] * b[j];
        }
    }
#pragma unroll
    for (int i = 0; i < 4; ++i) {
        const int m = m0 + ty * 4 + i;
#pragma unroll
        for (int j = 0; j < 4; ++j) {
            const int n = n0 + tx * 4 + j;
            C[(size_t)m * N + n] = acc[i][j] + bias[n];
        }
    }
}

// tanh(x) = 1 - 2/(exp2(2x*log2e)+1); ~1e-6 rel error, finite everywhere.
__device__ __forceinline__ float fast_tanh(float x)
{
    float e = __builtin_amdgcn_exp2f(x * 2.885390081777927f);
    return 1.0f - 2.0f * __builtin_amdgcn_rcpf(e + 1.0f);
}

__device__ __forceinline__ u64 ld_agent(const u64* p)
{
    return __hip_atomic_load(p, __ATOMIC_RELAXED, __HIP_MEMORY_SCOPE_AGENT);
}

__device__ __forceinline__ int is_poison(u64 x0, u64 x1)
{
    return ((unsigned)x0 == SENT) | ((unsigned)(x0 >> 32) == SENT) |
           ((unsigned)x1 == SENT) | ((unsigned)(x1 >> 32) == SENT);
}

// ---------------------------------------------------------------------------
// Persistent RNN scan, R10 = R9 (flag-dataflow, no per-step barrier) with the
// single-outstanding poll replaced by COMPILER-TRACKED pipelined polling.
// R6/R9 evidence: three different sync protocols all give ~4500 cy/step with
// only ~540 cy VALU -> the stall is exchange visibility + discovery.  With a
// one-outstanding poll the sampling period is a full L3 RTT R, and the step
// gates on the MAX over the 64 lanes of the last-arriving chunk's wave, so
// discovery adds ~R (~600-900 cy) beyond visibility.  Attack that term:
//
//   (a) DEPTH-2 PING-PONG POLL: two outstanding load-pairs of the same
//       address; check the older while the newer flies -> sampling period
//       ~R/2.  Pure C: the compiler tracks in-flight destinations and emits
//       counted waitcnts (R8's crash was asm-issued loads whose dests the
//       allocator reused -- compiler-issued loads cannot have that bug).
//   (b) SOUND NEXT-SLOT PREFETCH: after the producer stores, issue slot
//       (t+1) loads into loop-carried variables; at step t+1 check them
//       before polling.  The step-gating (late) block issues this AFTER the
//       leaders stored h(t+1) -> it skips the poll round entirely.  Any
//       early/partial sample reads poison -> falls through to (a).  No
//       stale-h hazard: slot (t+1)&7 was re-poisoned by every block >=3
//       steps (~5us) earlier (skew<=1), the same visibility class the base
//       poll already relies on (5-step-old poison).
//
//   Fast path issues ZERO poll loads for slot t (prefetch pair only) ->
//   less L3 poll pressure than R9.  All non-poison words are final values
//   (each ring word is written once between poisons), so accepting the
//   older ping-pong sample is exact.  Compute/order bit-identical to R6/R9.
// ---------------------------------------------------------------------------
__global__ __launch_bounds__(SCAN_T, 2) void rnn_scan(
    const int*  __restrict__ seq,
    const float* __restrict__ waa,
    const float* __restrict__ P,
    float* __restrict__ H,                 // (SEQ+1) x HID; plain (not polled)
    unsigned* __restrict__ ring)           // NREP x NSLOT x HID
{
    const int b    = blockIdx.x;
    const int tid  = threadIdx.x;
    const int wv   = tid >> 6;        // wave id 0..7
    const int lane = tid & 63;
    const int R0   = b * ROWS_PB + wv * 4;   // first of this wave's 4 rows
    const int rep  = b & (NREP - 1);

    __shared__ float hbuf[2][HID];    // 16 KB parity double-buffer
    __shared__ int   flg[2][8];       // per-parity, per-chunk "staged@step"

    // One-time weight load: w[i][4j+e] = waa[R0+i][256j+4*lane+e].
    float w0[32], w1[32], w2[32], w3[32];
#pragma unroll
    for (int j = 0; j < 8; ++j) {
        const float* base = waa + 256 * j + 4 * lane;
        float4 a = *(const float4*)(base + (size_t)(R0 + 0) * HID);
        float4 c = *(const float4*)(base + (size_t)(R0 + 1) * HID);
        float4 d = *(const float4*)(base + (size_t)(R0 + 2) * HID);
        float4 e = *(const float4*)(base + (size_t)(R0 + 3) * HID);
        w0[4*j+0]=a.x; w0[4*j+1]=a.y; w0[4*j+2]=a.z; w0[4*j+3]=a.w;
        w1[4*j+0]=c.x; w1[4*j+1]=c.y; w1[4*j+2]=c.z; w1[4*j+3]=c.w;
        w2[4*j+0]=d.x; w2[4*j+1]=d.y; w2[4*j+2]=d.z; w2[4*j+3]=d.w;
        w3[4*j+0]=e.x; w3[4*j+1]=e.y; w3[4*j+2]=e.z; w3[4*j+3]=e.w;
    }
#pragma unroll
    for (int k = 0; k < 32; ++k) {
        asm volatile("" : "+v"(w0[k])); asm volatile("" : "+v"(w1[k]));
        asm volatile("" : "+v"(w2[k])); asm volatile("" : "+v"(w3[k]));
    }

    if (tid < 16) ((int*)flg)[tid] = -1;
    __syncthreads();                  // the ONLY barrier (flag init)

    unsigned* myring = ring + (size_t)rep * NSLOT * HID;

    // Loop-carried prefetch pair; poison-init -> step 0 takes the poll path
    // (slot 0 is pre-zeroed h0, so that poll returns immediately).
    u64 c0 = ~0ull, c1 = ~0ull;

#pragma unroll 1
    for (int t = 0; t < SEQ; ++t) {
        // xa for this step (read-only, cached) -- overlaps the poll.
        const int ch = seq[t];
        float xav = 0.f;
        if (lane < 4) xav = P[(size_t)ch * HID + R0 + lane];

        // --- acquire my 4 words of slot t&7 ---
        u64 x0, x1;
        if (!is_poison(c0, c1)) {
            x0 = c0; x1 = c1;               // prefetch hit: zero poll loads
        } else {
            const u64* p8 = (const u64*)
                (myring + (size_t)(t & (NSLOT - 1)) * HID + tid * 4);
            // depth-2 ping-pong: check older sample while newer is in flight
            u64 a0 = ld_agent(p8 + 0), a1 = ld_agent(p8 + 1);
            u64 b0 = ld_agent(p8 + 0), b1 = ld_agent(p8 + 1);
            for (;;) {
                if (!is_poison(a0, a1)) { x0 = a0; x1 = a1; break; }
                a0 = ld_agent(p8 + 0); a1 = ld_agent(p8 + 1);
                if (!is_poison(b0, b1)) { x0 = b0; x1 = b1; break; }
                b0 = ld_agent(p8 + 0); b1 = ld_agent(p8 + 1);
            }
        }
        uint4v v;
        v.x = (unsigned)x0; v.y = (unsigned)(x0 >> 32);
        v.z = (unsigned)x1; v.w = (unsigned)(x1 >> 32);
        *(uint4v*)&hbuf[t & 1][tid * 4] = v;   // 16B stride: conflict-free

        // publish chunk wv for parity t&1 (data-before-flag via lgkmcnt(0))
        asm volatile("s_waitcnt lgkmcnt(0)" ::: "memory");
        if (lane == 0) *(volatile int*)&flg[t & 1][wv] = t;

        // --- per-chunk gated compute: 8x {spin flag; b128 read; 16 FMA} ---
        float a0 = 0.f, a1 = 0.f, a2 = 0.f, a3 = 0.f;
        const float* hb = &hbuf[t & 1][4 * lane];
#pragma unroll
        for (int j = 0; j < 8; ++j) {
            while (*(volatile int*)&flg[t & 1][j] != t) { }
            asm volatile("" ::: "memory");   // no hbuf-read hoist above spin
            float4 hv = *(const float4*)(hb + 256 * j);
            a0 += w0[4*j+0]*hv.x + w0[4*j+1]*hv.y + w0[4*j+2]*hv.z + w0[4*j+3]*hv.w;
            a1 += w1[4*j+0]*hv.x + w1[4*j+1]*hv.y + w1[4*j+2]*hv.z + w1[4*j+3]*hv.w;
            a2 += w2[4*j+0]*hv.x + w2[4*j+1]*hv.y + w2[4*j+2]*hv.z + w2[4*j+3]*hv.w;
            a3 += w3[4*j+0]*hv.x + w3[4*j+1]*hv.y + w3[4*j+2]*hv.z + w3[4*j+3]*hv.w;
        }
        // Paired butterfly: row (lane&3)'s full sum ends in lane l.
        a0 += __shfl_xor(a0, 1, 64);
        a1 += __shfl_xor(a1, 1, 64);
        a2 += __shfl_xor(a2, 1, 64);
        a3 += __shfl_xor(a3, 1, 64);
        float m01 = (lane & 1) ? a1 : a0;
        float m23 = (lane & 1) ? a3 : a2;
        m01 += __shfl_xor(m01, 2, 64);
        m23 += __shfl_xor(m23, 2, 64);
        float m = (lane & 2) ? m23 : m01;
        m += __shfl_xor(m, 4, 64);
        m += __shfl_xor(m, 8, 64);
        m += __shfl_xor(m, 16, 64);
        m += __shfl_xor(m, 32, 64);

        if (lane < 4) {
            float hn = fast_tanh(xav + m);
            const unsigned hu = __float_as_uint(hn);
            const int row = R0 + lane;
            const int s1 = (t + 1) & (NSLOT - 1);
            const int s5 = (t + 5) & (NSLOT - 1);
            // signals to ALL replicas first (consumer-critical), ...
#pragma unroll
            for (int r = 0; r < NREP; ++r)
                __hip_atomic_store(ring + ((size_t)r * NSLOT + s1) * HID + row,
                                   hu, __ATOMIC_RELAXED,
                                   __HIP_MEMORY_SCOPE_AGENT);
            // ... then poisons (needed 4 steps out), then plain H row.
#pragma unroll
            for (int r = 0; r < NREP; ++r)
                __hip_atomic_store(ring + ((size_t)r * NSLOT + s5) * HID + row,
                                   SENT, __ATOMIC_RELAXED,
                                   __HIP_MEMORY_SCOPE_AGENT);
            H[(size_t)(t + 1) * HID + row] = hn;   // epilogue GEMM input
        }

        // --- sound prefetch of slot t+1 (compiler-tracked, loop-carried).
        //     Issued after the signal stores; sampled at the top of t+1.
        //     Own-window threads will read their own poison/fresh rows and
        //     simply fall back to the poll -- never incorrect.
        if (t + 1 < SEQ) {
            const u64* pn = (const u64*)
                (myring + (size_t)((t + 1) & (NSLOT - 1)) * HID + tid * 4);
            c0 = ld_agent(pn + 0);
            c1 = ld_agent(pn + 1);
        }
        // store IS the signal; unique addresses per slot -> race-free
    }
}

__global__ void copy_h(const float* __restrict__ src, float* __restrict__ dst)
{
    int i = blockIdx.x * blockDim.x + threadIdx.x;
    if (i < HID) dst[i] = src[i];
}

// ---------------------------------------------------------------------------
extern "C" void kernel_launch(void* const* d_in, const int* in_sizes, int n_in,
                              void* d_out, int out_size, void* d_ws, size_t ws_size,
                              hipStream_t stream)
{
    const int*   seq  = (const int*)  d_in[0];
    const float* emb  = (const float*)d_in[1];
    const float* wax  = (const float*)d_in[2];
    const float* waxb = (const float*)d_in[3];
    const float* waa  = (const float*)d_in[4];
    const float* wya  = (const float*)d_in[5];
    const float* wyab = (const float*)d_in[6];
    float* out = (float*)d_out;

    // ws layout: H[(SEQ+1)][HID] fp32 | P[NCH][HID] fp32 | ring[4][8][HID] u32
    float*    H    = (float*)d_ws;
    float*    P    = (float*)((char*)d_ws + (size_t)(SEQ + 1) * HID * sizeof(float));
    unsigned* ring = (unsigned*)(P + (size_t)NCH * HID);

    // Re-init every call: ring all-poison, then slot 0 of each replica = h0 = 0.
    (void)hipMemsetAsync(ring, 0xFF, (size_t)NREP * NSLOT * HID * sizeof(unsigned), stream);
    for (int r = 0; r < NREP; ++r)
        (void)hipMemsetAsync(ring + (size_t)r * NSLOT * HID, 0,
                             HID * sizeof(unsigned), stream);

    // P = emb @ wax^T + wax_b   (M=256, N=2048, K=1024)
    dim3 gA(NCH / 64, HID / 64);
    gemm_tn<<<gA, 256, 0, stream>>>(emb, wax, waxb, P, NCH, HID, EMB);

    // Sequential recurrence (persistent, flag-dataflow + ring poison sync).
    rnn_scan<<<SCAN_B, SCAN_T, 0, stream>>>(seq, waa, P, H, ring);

    // out = H[1..SEQ] @ wya^T + wya_b   (M=8192, N=256, K=2048)
    dim3 gC(SEQ / 64, NCH / 64);
    gemm_tn<<<gC, 256, 0, stream>>>(H + HID, wya, wyab, out, SEQ, NCH, HID);

    // h_final = H[SEQ] -> tail of d_out
    copy_h<<<(HID + 255) / 256, 256, 0, stream>>>(H + (size_t)SEQ * HID,
                                                  out + (size_t)SEQ * NCH);
}

// Round 5
// 20343.776 us; speedup vs baseline: 1.2352x; 1.2352x over previous
//
#include <hip/hip_runtime.h>
#include <stdint.h>

#define SEQ 8192
#define EMB 1024
#define HID 2048
#define NCH 256

#define SCAN_B 64                   // persistent blocks (co-resident, proven R1-R6)
#define SCAN_T 576                  // 8 compute waves + 1 store wave
#define ROWS_PB (HID / SCAN_B)      // 32 rows per block (4 per compute wave)
#define SENT 0xFFFFFFFFu            // poison: tanh never produces this pattern
#define NREP 4                      // ring replicas (spread L3 line ownership)
#define NSLOT 8                     // ring slots (skew<=1 proven; margin 4)

typedef unsigned uint4v __attribute__((ext_vector_type(4)));

// ---------------------------------------------------------------------------
// Generic fp32 "TN" GEMM: C[m][n] = bias[n] + dot(X[m][:], W[n][:])
// ---------------------------------------------------------------------------
__global__ __launch_bounds__(256) void gemm_tn(const float* __restrict__ X,
                                               const float* __restrict__ W,
                                               const float* __restrict__ bias,
                                               float* __restrict__ C,
                                               int M, int N, int K)
{
    __shared__ float Xs[16][68];
    __shared__ float Ws[16][68];
    const int m0 = blockIdx.x * 64, n0 = blockIdx.y * 64;
    const int tid  = threadIdx.x;
    const int lrow = tid >> 2;
    const int kq   = (tid & 3) * 4;
    const int tx   = tid & 15, ty = tid >> 4;
    float acc[4][4] = {};
    const float* Xp = X + (size_t)(m0 + lrow) * K + kq;
    const float* Wp = W + (size_t)(n0 + lrow) * K + kq;

    for (int k0 = 0; k0 < K; k0 += 16) {
        float4 xv = *(const float4*)(Xp + k0);
        float4 wv = *(const float4*)(Wp + k0);
        __syncthreads();
        Xs[kq+0][lrow] = xv.x; Xs[kq+1][lrow] = xv.y;
        Xs[kq+2][lrow] = xv.z; Xs[kq+3][lrow] = xv.w;
        Ws[kq+0][lrow] = wv.x; Ws[kq+1][lrow] = wv.y;
        Ws[kq+2][lrow] = wv.z; Ws[kq+3][lrow] = wv.w;
        __syncthreads();
#pragma unroll
        for (int kk = 0; kk < 16; ++kk) {
            float4 av = *(const float4*)&Xs[kk][ty * 4];
            float4 bv = *(const float4*)&Ws[kk][tx * 4];
            float a[4] = {av.x, av.y, av.z, av.w};
            float b[4] = {bv.x, bv.y, bv.z, bv.w};
#pragma unroll
            for (int i = 0; i < 4; ++i)
#pragma unroll
                for (int j = 0; j < 4; ++j)
                    acc[i][j] += a[i] * b[j];
        }
    }
#pragma unroll
    for (int i = 0; i < 4; ++i) {
        const int m = m0 + ty * 4 + i;
#pragma unroll
        for (int j = 0; j < 4; ++j) {
            const int n = n0 + tx * 4 + j;
            C[(size_t)m * N + n] = acc[i][j] + bias[n];
        }
    }
}

// tanh(x) = 1 - 2/(exp2(2x*log2e)+1); ~1e-6 rel error, finite everywhere.
__device__ __forceinline__ float fast_tanh(float x)
{
    float e = __builtin_amdgcn_exp2f(x * 2.885390081777927f);
    return 1.0f - 2.0f * __builtin_amdgcn_rcpf(e + 1.0f);
}

// ---------------------------------------------------------------------------
// Persistent RNN scan, R11 = R9 (flag-dataflow) + PRODUCER/CONSUMER WAVE
// SPLIT.  Root cause identified in R10's counters: vmcnt retires in issue
// order, so a wave that issued ring/H stores cannot complete a later poll
// load without draining its own cross-XCD store-acks (~600-1000 cy) -- this
// per-wave serialization was in EVERY prior round and explains why three
// different sync protocols all measured ~4500 cy/step.
//
//   - Waves 0..7 (512 threads): identical compute to R9 (poll, stage, flag,
//     gated FMA, butterfly, tanh) but issue ZERO global stores.  After the
//     butterfly, lanes 0-3 ds_write hn to hnbuf[wv*4+lane], lgkm-fence, and
//     lane 0 publishes sflg[wv] = t (step-tagged).
//   - Wave 8 (store wave): spins on sflg, then issues ALL global stores
//     (4 ring signals + 4 poisons per row, plus the H row).  Its store-acks
//     accumulate in ITS vmem queue and never touch the compute waves.
//   - P load moved AFTER staging/flag-publish: consumed only at tanh, its
//     latency hides under the 8-chunk FMA window, and the next step's poll
//     vmcnt(0) finds it long retired.  Compute-wave vmem queue per step:
//     the poll load + one P load.  Nothing else.
//
//   Deadlock-freedom / handoff safety: all rows flow through the ring
//   (R9 dataflow), so compute waves cannot pass step t+1's poll until their
//   OWN store wave's step-t signals are visible.  Hence sflg advances to
//   t+1 only after the store wave consumed step t (no skipped tags), and
//   hnbuf for t+1 is written only after the store wave read step t's
//   values.  Store-wave lag is bounded by the same gating, so ring signal/
//   poison timing classes are unchanged from the proven protocol.
// ---------------------------------------------------------------------------
__global__ __launch_bounds__(SCAN_T, 2) void rnn_scan(
    const int*  __restrict__ seq,
    const float* __restrict__ waa,
    const float* __restrict__ P,
    float* __restrict__ H,                 // (SEQ+1) x HID; plain (not polled)
    unsigned* __restrict__ ring)           // NREP x NSLOT x HID
{
    const int b    = blockIdx.x;
    const int tid  = threadIdx.x;
    const int wv   = tid >> 6;        // wave id 0..8
    const int lane = tid & 63;
    const int rep  = b & (NREP - 1);

    __shared__ float hbuf[2][HID];    // 16 KB parity double-buffer
    __shared__ int   flg[2][8];       // per-parity, per-chunk "staged@step"
    __shared__ float hnbuf[ROWS_PB];  // compute->store wave handoff (32 rows)
    __shared__ int   sflg[8];         // per-compute-wave "hn ready@step"

    if (tid < 16) ((int*)flg)[tid] = -1;
    if (tid >= 16 && tid < 24) sflg[tid - 16] = -1;
    __syncthreads();                  // the ONLY barrier (flag init)

    if (wv == 8) {
        // ================= store wave: issues ALL global stores ==========
        const int l   = lane & 31;
        const int row = b * ROWS_PB + l;
        const int fw  = (lane >> 2) & 7;  // wave whose rows this lane serves
#pragma unroll 1
        for (int t = 0; t < SEQ; ++t) {
            while (*(volatile int*)&sflg[fw] != t) { }
            asm volatile("" ::: "memory");   // no hnbuf-read hoist above spin
            if (lane < 32) {
                const float hn = hnbuf[l];
                const unsigned hu = __float_as_uint(hn);
                const int s1 = (t + 1) & (NSLOT - 1);
                const int s5 = (t + 5) & (NSLOT - 1);
#pragma unroll
                for (int r = 0; r < NREP; ++r)
                    __hip_atomic_store(ring + ((size_t)r * NSLOT + s1) * HID + row,
                                       hu, __ATOMIC_RELAXED,
                                       __HIP_MEMORY_SCOPE_AGENT);
#pragma unroll
                for (int r = 0; r < NREP; ++r)
                    __hip_atomic_store(ring + ((size_t)r * NSLOT + s5) * HID + row,
                                       SENT, __ATOMIC_RELAXED,
                                       __HIP_MEMORY_SCOPE_AGENT);
                H[(size_t)(t + 1) * HID + row] = hn;   // epilogue GEMM input
            }
        }
        return;
    }

    // ==================== compute waves 0..7 (512 threads) ===============
    const int R0 = b * ROWS_PB + wv * 4;     // first of this wave's 4 rows

    // One-time weight load: w[i][4j+e] = waa[R0+i][256j+4*lane+e].
    float w0[32], w1[32], w2[32], w3[32];
#pragma unroll
    for (int j = 0; j < 8; ++j) {
        const float* base = waa + 256 * j + 4 * lane;
        float4 a = *(const float4*)(base + (size_t)(R0 + 0) * HID);
        float4 c = *(const float4*)(base + (size_t)(R0 + 1) * HID);
        float4 d = *(const float4*)(base + (size_t)(R0 + 2) * HID);
        float4 e = *(const float4*)(base + (size_t)(R0 + 3) * HID);
        w0[4*j+0]=a.x; w0[4*j+1]=a.y; w0[4*j+2]=a.z; w0[4*j+3]=a.w;
        w1[4*j+0]=c.x; w1[4*j+1]=c.y; w1[4*j+2]=c.z; w1[4*j+3]=c.w;
        w2[4*j+0]=d.x; w2[4*j+1]=d.y; w2[4*j+2]=d.z; w2[4*j+3]=d.w;
        w3[4*j+0]=e.x; w3[4*j+1]=e.y; w3[4*j+2]=e.z; w3[4*j+3]=e.w;
    }
#pragma unroll
    for (int k = 0; k < 32; ++k) {
        asm volatile("" : "+v"(w0[k])); asm volatile("" : "+v"(w1[k]));
        asm volatile("" : "+v"(w2[k])); asm volatile("" : "+v"(w3[k]));
    }

    unsigned* myring = ring + (size_t)rep * NSLOT * HID;

#pragma unroll 1
    for (int t = 0; t < SEQ; ++t) {
        // --- poll my 4 words of slot t&7; load+wait in ONE asm block.
        //     This wave's vmem queue holds no stores -> vmcnt(0) waits for
        //     THIS load only (plus last step's long-retired P load).
        uint4v v;
        const unsigned* pp = myring + (size_t)(t & (NSLOT - 1)) * HID + tid * 4;
        do {
            asm volatile("global_load_dwordx4 %0, %1, off sc0 sc1\n\t"
                         "s_waitcnt vmcnt(0)"
                         : "=v"(v) : "v"(pp) : "memory");
        } while (v.x == SENT || v.y == SENT || v.z == SENT || v.w == SENT);
        *(uint4v*)&hbuf[t & 1][tid * 4] = v;   // 16B stride: conflict-free

        // publish chunk wv for parity t&1 (data-before-flag via lgkmcnt(0))
        asm volatile("s_waitcnt lgkmcnt(0)" ::: "memory");
        if (lane == 0) *(volatile int*)&flg[t & 1][wv] = t;

        // xa for this step: issued now, consumed at tanh -> latency hides
        // under the 8-chunk FMA window below.
        const int ch = seq[t];
        float xav = 0.f;
        if (lane < 4) xav = P[(size_t)ch * HID + R0 + lane];

        // --- per-chunk gated compute: 8x {spin flag; b128 read; 16 FMA} ---
        float a0 = 0.f, a1 = 0.f, a2 = 0.f, a3 = 0.f;
        const float* hb = &hbuf[t & 1][4 * lane];
#pragma unroll
        for (int j = 0; j < 8; ++j) {
            while (*(volatile int*)&flg[t & 1][j] != t) { }
            asm volatile("" ::: "memory");   // no hbuf-read hoist above spin
            float4 hv = *(const float4*)(hb + 256 * j);
            a0 += w0[4*j+0]*hv.x + w0[4*j+1]*hv.y + w0[4*j+2]*hv.z + w0[4*j+3]*hv.w;
            a1 += w1[4*j+0]*hv.x + w1[4*j+1]*hv.y + w1[4*j+2]*hv.z + w1[4*j+3]*hv.w;
            a2 += w2[4*j+0]*hv.x + w2[4*j+1]*hv.y + w2[4*j+2]*hv.z + w2[4*j+3]*hv.w;
            a3 += w3[4*j+0]*hv.x + w3[4*j+1]*hv.y + w3[4*j+2]*hv.z + w3[4*j+3]*hv.w;
        }
        // Paired butterfly: row (lane&3)'s full sum ends in lane l.
        a0 += __shfl_xor(a0, 1, 64);
        a1 += __shfl_xor(a1, 1, 64);
        a2 += __shfl_xor(a2, 1, 64);
        a3 += __shfl_xor(a3, 1, 64);
        float m01 = (lane & 1) ? a1 : a0;
        float m23 = (lane & 1) ? a3 : a2;
        m01 += __shfl_xor(m01, 2, 64);
        m23 += __shfl_xor(m23, 2, 64);
        float m = (lane & 2) ? m23 : m01;
        m += __shfl_xor(m, 4, 64);
        m += __shfl_xor(m, 8, 64);
        m += __shfl_xor(m, 16, 64);
        m += __shfl_xor(m, 32, 64);

        // --- handoff to store wave (LDS only; zero global stores here) ---
        if (lane < 4) {
            float hn = fast_tanh(xav + m);
            hnbuf[wv * 4 + lane] = hn;
        }
        asm volatile("s_waitcnt lgkmcnt(0)" ::: "memory");
        if (lane == 0) *(volatile int*)&sflg[wv] = t;
    }
}

__global__ void copy_h(const float* __restrict__ src, float* __restrict__ dst)
{
    int i = blockIdx.x * blockDim.x + threadIdx.x;
    if (i < HID) dst[i] = src[i];
}

// ---------------------------------------------------------------------------
extern "C" void kernel_launch(void* const* d_in, const int* in_sizes, int n_in,
                              void* d_out, int out_size, void* d_ws, size_t ws_size,
                              hipStream_t stream)
{
    const int*   seq  = (const int*)  d_in[0];
    const float* emb  = (const float*)d_in[1];
    const float* wax  = (const float*)d_in[2];
    const float* waxb = (const float*)d_in[3];
    const float* waa  = (const float*)d_in[4];
    const float* wya  = (const float*)d_in[5];
    const float* wyab = (const float*)d_in[6];
    float* out = (float*)d_out;

    // ws layout: H[(SEQ+1)][HID] fp32 | P[NCH][HID] fp32 | ring[4][8][HID] u32
    float*    H    = (float*)d_ws;
    float*    P    = (float*)((char*)d_ws + (size_t)(SEQ + 1) * HID * sizeof(float));
    unsigned* ring = (unsigned*)(P + (size_t)NCH * HID);

    // Re-init every call: ring all-poison, then slot 0 of each replica = h0 = 0.
    (void)hipMemsetAsync(ring, 0xFF, (size_t)NREP * NSLOT * HID * sizeof(unsigned), stream);
    for (int r = 0; r < NREP; ++r)
        (void)hipMemsetAsync(ring + (size_t)r * NSLOT * HID, 0,
                             HID * sizeof(unsigned), stream);

    // P = emb @ wax^T + wax_b   (M=256, N=2048, K=1024)
    dim3 gA(NCH / 64, HID / 64);
    gemm_tn<<<gA, 256, 0, stream>>>(emb, wax, waxb, P, NCH, HID, EMB);

    // Sequential recurrence (persistent, wave-split + ring poison sync).
    rnn_scan<<<SCAN_B, SCAN_T, 0, stream>>>(seq, waa, P, H, ring);

    // out = H[1..SEQ] @ wya^T + wya_b   (M=8192, N=256, K=2048)
    dim3 gC(SEQ / 64, NCH / 64);
    gemm_tn<<<gC, 256, 0, stream>>>(H + HID, wya, wyab, out, SEQ, NCH, HID);

    // h_final = H[SEQ] -> tail of d_out
    copy_h<<<(HID + 255) / 256, 256, 0, stream>>>(H + (size_t)SEQ * HID,
                                                  out + (size_t)SEQ * NCH);
}

// Round 6
// 17201.282 us; speedup vs baseline: 1.4608x; 1.1827x over previous
//
#include <hip/hip_runtime.h>
#include <stdint.h>

#define SEQ 8192
#define EMB 1024
#define HID 2048
#define NCH 256

#define SCAN_B 64                   // persistent blocks (co-resident, proven R1-R6)
#define SCAN_T 512                  // 8 waves/block
#define ROWS_PB (HID / SCAN_B)      // 32 rows per block (4 per wave)
#define SENT 0xFFFFFFFFu            // poison: tanh never produces this pattern
#define NREP 4                      // ring replicas (spread L3 line ownership)
#define NSLOT 8                     // ring slots (skew<=1 proven; margin 4)

typedef unsigned uint4v __attribute__((ext_vector_type(4)));
typedef unsigned long long u64;

// ---------------------------------------------------------------------------
// Generic fp32 "TN" GEMM: C[m][n] = bias[n] + dot(X[m][:], W[n][:])
// ---------------------------------------------------------------------------
__global__ __launch_bounds__(256) void gemm_tn(const float* __restrict__ X,
                                               const float* __restrict__ W,
                                               const float* __restrict__ bias,
                                               float* __restrict__ C,
                                               int M, int N, int K)
{
    __shared__ float Xs[16][68];
    __shared__ float Ws[16][68];
    const int m0 = blockIdx.x * 64, n0 = blockIdx.y * 64;
    const int tid  = threadIdx.x;
    const int lrow = tid >> 2;
    const int kq   = (tid & 3) * 4;
    const int tx   = tid & 15, ty = tid >> 4;
    float acc[4][4] = {};
    const float* Xp = X + (size_t)(m0 + lrow) * K + kq;
    const float* Wp = W + (size_t)(n0 + lrow) * K + kq;

    for (int k0 = 0; k0 < K; k0 += 16) {
        float4 xv = *(const float4*)(Xp + k0);
        float4 wv = *(const float4*)(Wp + k0);
        __syncthreads();
        Xs[kq+0][lrow] = xv.x; Xs[kq+1][lrow] = xv.y;
        Xs[kq+2][lrow] = xv.z; Xs[kq+3][lrow] = xv.w;
        Ws[kq+0][lrow] = wv.x; Ws[kq+1][lrow] = wv.y;
        Ws[kq+2][lrow] = wv.z; Ws[kq+3][lrow] = wv.w;
        __syncthreads();
#pragma unroll
        for (int kk = 0; kk < 16; ++kk) {
            float4 av = *(const float4*)&Xs[kk][ty * 4];
            float4 bv = *(const float4*)&Ws[kk][tx * 4];
            float a[4] = {av.x, av.y, av.z, av.w};
            float b[4] = {bv.x, bv.y, bv.z, bv.w};
#pragma unroll
            for (int i = 0; i < 4; ++i)
#pragma unroll
                for (int j = 0; j < 4; ++j)
                    acc[i][j] += a[i] * b[j];
        }
    }
#pragma unroll
    for (int i = 0; i < 4; ++i) {
        const int m = m0 + ty * 4 + i;
#pragma unroll
        for (int j = 0; j < 4; ++j) {
            const int n = n0 + tx * 4 + j;
            C[(size_t)m * N + n] = acc[i][j] + bias[n];
        }
    }
}

// tanh(x) = 1 - 2/(exp2(2x*log2e)+1); ~1e-6 rel error, finite everywhere.
__device__ __forceinline__ float fast_tanh(float x)
{
    float e = __builtin_amdgcn_exp2f(x * 2.885390081777927f);
    return 1.0f - 2.0f * __builtin_amdgcn_rcpf(e + 1.0f);
}

__device__ __forceinline__ u64 ld_agent(const u64* p)
{
    return __hip_atomic_load(p, __ATOMIC_RELAXED, __HIP_MEMORY_SCOPE_AGENT);
}

__device__ __forceinline__ int is_poison(u64 x0, u64 x1)
{
    return ((unsigned)x0 == SENT) | ((unsigned)(x0 >> 32) == SENT) |
           ((unsigned)x1 == SENT) | ((unsigned)(x1 >> 32) == SENT);
}

// ---------------------------------------------------------------------------
// Persistent RNN scan, R12 = R9 (flag-dataflow, stores in-wave -- R11 proved
// the signal must be issued by the computing wave immediately) + two changes:
//
//   (a) DEPTH-3 PING-PONG POLL, inside the poll only (R10's failure was the
//       cross-store prefetch at poll ENTRY, which forced a store-ack drain;
//       the ping-pong itself never ran cleanly).  Three sample-pairs of the
//       SAME address rotate: check oldest while two fly.  Compiler-tracked
//       loads -> counted vmcnt(4) waits, registers kept live by the
//       allocator (sound, unlike R8's asm-issued loads).  Sampling period
//       drops from ~RTT to ~RTT/3; the step gates on the max over 512 poll
//       windows, so expected discovery improves by a few hundred cycles.
//       Every non-poison sample is the final value (each ring word written
//       once between poisons) -> accepting any sample is exact.  Leftover
//       in-flight loads retire naturally long before their registers are
//       reused (next vmem use is a full step away).
//   (b) s_setprio(1) around the post-discovery tail (butterfly + tanh +
//       ring stores): tail-phase waves -- which carry the cross-block
//       serial chain -- win SIMD issue arbitration over prio-0 pollers.
//
//   Everything else is R9 verbatim: per-chunk LDS flags instead of a
//   barrier (parity-reuse proof in R9 header), NREP=4/NSLOT=8 ring with
//   poison at distance 5 / reuse at 8, skew<=1, bit-identical FP order.
// ---------------------------------------------------------------------------
__global__ __launch_bounds__(SCAN_T, 2) void rnn_scan(
    const int*  __restrict__ seq,
    const float* __restrict__ waa,
    const float* __restrict__ P,
    float* __restrict__ H,                 // (SEQ+1) x HID; plain (not polled)
    unsigned* __restrict__ ring)           // NREP x NSLOT x HID
{
    const int b    = blockIdx.x;
    const int tid  = threadIdx.x;
    const int wv   = tid >> 6;        // wave id 0..7
    const int lane = tid & 63;
    const int R0   = b * ROWS_PB + wv * 4;   // first of this wave's 4 rows
    const int rep  = b & (NREP - 1);

    __shared__ float hbuf[2][HID];    // 16 KB parity double-buffer
    __shared__ int   flg[2][8];       // per-parity, per-chunk "staged@step"

    // One-time weight load: w[i][4j+e] = waa[R0+i][256j+4*lane+e].
    float w0[32], w1[32], w2[32], w3[32];
#pragma unroll
    for (int j = 0; j < 8; ++j) {
        const float* base = waa + 256 * j + 4 * lane;
        float4 a = *(const float4*)(base + (size_t)(R0 + 0) * HID);
        float4 c = *(const float4*)(base + (size_t)(R0 + 1) * HID);
        float4 d = *(const float4*)(base + (size_t)(R0 + 2) * HID);
        float4 e = *(const float4*)(base + (size_t)(R0 + 3) * HID);
        w0[4*j+0]=a.x; w0[4*j+1]=a.y; w0[4*j+2]=a.z; w0[4*j+3]=a.w;
        w1[4*j+0]=c.x; w1[4*j+1]=c.y; w1[4*j+2]=c.z; w1[4*j+3]=c.w;
        w2[4*j+0]=d.x; w2[4*j+1]=d.y; w2[4*j+2]=d.z; w2[4*j+3]=d.w;
        w3[4*j+0]=e.x; w3[4*j+1]=e.y; w3[4*j+2]=e.z; w3[4*j+3]=e.w;
    }
#pragma unroll
    for (int k = 0; k < 32; ++k) {
        asm volatile("" : "+v"(w0[k])); asm volatile("" : "+v"(w1[k]));
        asm volatile("" : "+v"(w2[k])); asm volatile("" : "+v"(w3[k]));
    }

    if (tid < 16) ((int*)flg)[tid] = -1;
    __syncthreads();                  // the ONLY barrier (flag init)

    unsigned* myring = ring + (size_t)rep * NSLOT * HID;

#pragma unroll 1
    for (int t = 0; t < SEQ; ++t) {
        // xa for this step (read-only, cached) -- overlaps the poll.
        const int ch = seq[t];
        float xav = 0.f;
        if (lane < 4) xav = P[(size_t)ch * HID + R0 + lane];

        // --- depth-3 ping-pong poll of my 4 words of slot t&7 ---
        u64 x0, x1;
        {
            const u64* p8 = (const u64*)
                (myring + (size_t)(t & (NSLOT - 1)) * HID + tid * 4);
            u64 a0 = ld_agent(p8 + 0), a1 = ld_agent(p8 + 1);
            u64 b0 = ld_agent(p8 + 0), b1 = ld_agent(p8 + 1);
            u64 c0 = ld_agent(p8 + 0), c1 = ld_agent(p8 + 1);
            for (;;) {
                if (!is_poison(a0, a1)) { x0 = a0; x1 = a1; break; }
                a0 = ld_agent(p8 + 0); a1 = ld_agent(p8 + 1);
                if (!is_poison(b0, b1)) { x0 = b0; x1 = b1; break; }
                b0 = ld_agent(p8 + 0); b1 = ld_agent(p8 + 1);
                if (!is_poison(c0, c1)) { x0 = c0; x1 = c1; break; }
                c0 = ld_agent(p8 + 0); c1 = ld_agent(p8 + 1);
            }
        }
        uint4v v;
        v.x = (unsigned)x0; v.y = (unsigned)(x0 >> 32);
        v.z = (unsigned)x1; v.w = (unsigned)(x1 >> 32);
        *(uint4v*)&hbuf[t & 1][tid * 4] = v;   // 16B stride: conflict-free

        // publish chunk wv for parity t&1 (data-before-flag via lgkmcnt(0))
        asm volatile("s_waitcnt lgkmcnt(0)" ::: "memory");
        if (lane == 0) *(volatile int*)&flg[t & 1][wv] = t;

        // --- per-chunk gated compute: 8x {spin flag; b128 read; 16 FMA} ---
        float a0 = 0.f, a1 = 0.f, a2 = 0.f, a3 = 0.f;
        const float* hb = &hbuf[t & 1][4 * lane];
#pragma unroll
        for (int j = 0; j < 8; ++j) {
            while (*(volatile int*)&flg[t & 1][j] != t) { }
            asm volatile("" ::: "memory");   // no hbuf-read hoist above spin
            float4 hv = *(const float4*)(hb + 256 * j);
            a0 += w0[4*j+0]*hv.x + w0[4*j+1]*hv.y + w0[4*j+2]*hv.z + w0[4*j+3]*hv.w;
            a1 += w1[4*j+0]*hv.x + w1[4*j+1]*hv.y + w1[4*j+2]*hv.z + w1[4*j+3]*hv.w;
            a2 += w2[4*j+0]*hv.x + w2[4*j+1]*hv.y + w2[4*j+2]*hv.z + w2[4*j+3]*hv.w;
            a3 += w3[4*j+0]*hv.x + w3[4*j+1]*hv.y + w3[4*j+2]*hv.z + w3[4*j+3]*hv.w;
        }

        // --- tail carries the cross-block serial chain: boost priority ---
        __builtin_amdgcn_s_setprio(1);

        // Paired butterfly: row (lane&3)'s full sum ends in lane l.
        a0 += __shfl_xor(a0, 1, 64);
        a1 += __shfl_xor(a1, 1, 64);
        a2 += __shfl_xor(a2, 1, 64);
        a3 += __shfl_xor(a3, 1, 64);
        float m01 = (lane & 1) ? a1 : a0;
        float m23 = (lane & 1) ? a3 : a2;
        m01 += __shfl_xor(m01, 2, 64);
        m23 += __shfl_xor(m23, 2, 64);
        float m = (lane & 2) ? m23 : m01;
        m += __shfl_xor(m, 4, 64);
        m += __shfl_xor(m, 8, 64);
        m += __shfl_xor(m, 16, 64);
        m += __shfl_xor(m, 32, 64);

        if (lane < 4) {
            float hn = fast_tanh(xav + m);
            const unsigned hu = __float_as_uint(hn);
            const int row = R0 + lane;
            const int s1 = (t + 1) & (NSLOT - 1);
            const int s5 = (t + 5) & (NSLOT - 1);
            // signals to ALL replicas first (consumer-critical), ...
#pragma unroll
            for (int r = 0; r < NREP; ++r)
                __hip_atomic_store(ring + ((size_t)r * NSLOT + s1) * HID + row,
                                   hu, __ATOMIC_RELAXED,
                                   __HIP_MEMORY_SCOPE_AGENT);
            // ... then poisons (needed 4 steps out), then plain H row.
#pragma unroll
            for (int r = 0; r < NREP; ++r)
                __hip_atomic_store(ring + ((size_t)r * NSLOT + s5) * HID + row,
                                   SENT, __ATOMIC_RELAXED,
                                   __HIP_MEMORY_SCOPE_AGENT);
            H[(size_t)(t + 1) * HID + row] = hn;   // epilogue GEMM input
        }
        __builtin_amdgcn_s_setprio(0);
        // store IS the signal; unique addresses per slot -> race-free
    }
}

__global__ void copy_h(const float* __restrict__ src, float* __restrict__ dst)
{
    int i = blockIdx.x * blockDim.x + threadIdx.x;
    if (i < HID) dst[i] = src[i];
}

// ---------------------------------------------------------------------------
extern "C" void kernel_launch(void* const* d_in, const int* in_sizes, int n_in,
                              void* d_out, int out_size, void* d_ws, size_t ws_size,
                              hipStream_t stream)
{
    const int*   seq  = (const int*)  d_in[0];
    const float* emb  = (const float*)d_in[1];
    const float* wax  = (const float*)d_in[2];
    const float* waxb = (const float*)d_in[3];
    const float* waa  = (const float*)d_in[4];
    const float* wya  = (const float*)d_in[5];
    const float* wyab = (const float*)d_in[6];
    float* out = (float*)d_out;

    // ws layout: H[(SEQ+1)][HID] fp32 | P[NCH][HID] fp32 | ring[4][8][HID] u32
    float*    H    = (float*)d_ws;
    float*    P    = (float*)((char*)d_ws + (size_t)(SEQ + 1) * HID * sizeof(float));
    unsigned* ring = (unsigned*)(P + (size_t)NCH * HID);

    // Re-init every call: ring all-poison, then slot 0 of each replica = h0 = 0.
    (void)hipMemsetAsync(ring, 0xFF, (size_t)NREP * NSLOT * HID * sizeof(unsigned), stream);
    for (int r = 0; r < NREP; ++r)
        (void)hipMemsetAsync(ring + (size_t)r * NSLOT * HID, 0,
                             HID * sizeof(unsigned), stream);

    // P = emb @ wax^T + wax_b   (M=256, N=2048, K=1024)
    dim3 gA(NCH / 64, HID / 64);
    gemm_tn<<<gA, 256, 0, stream>>>(emb, wax, waxb, P, NCH, HID, EMB);

    // Sequential recurrence (persistent, flag-dataflow + ring poison sync).
    rnn_scan<<<SCAN_B, SCAN_T, 0, stream>>>(seq, waa, P, H, ring);

    // out = H[1..SEQ] @ wya^T + wya_b   (M=8192, N=256, K=2048)
    dim3 gC(SEQ / 64, NCH / 64);
    gemm_tn<<<gC, 256, 0, stream>>>(H + HID, wya, wyab, out, SEQ, NCH, HID);

    // h_final = H[SEQ] -> tail of d_out
    copy_h<<<(HID + 255) / 256, 256, 0, stream>>>(H + (size_t)SEQ * HID,
                                                  out + (size_t)SEQ * NCH);
}